// Round 6
// baseline (204.189 us; speedup 1.0000x reference)
//
#include <hip/hip_runtime.h>
#include <stdint.h>

// Problem constants
#define B_   32
#define T_   2048
#define E_   256
#define H_   256
#define LBL_ 20
#define M_   (B_ * T_)      // 65536 rows
#define NPACK_ 1536         // 2 dirs * 3 gates (i,g,o) * 256

typedef __attribute__((ext_vector_type(8))) short bf16x8;
typedef __attribute__((ext_vector_type(4))) float f32x4;

__device__ __forceinline__ unsigned short f2bf(float f) {
    union { float f; unsigned int u; } a; a.f = f;
    unsigned int u = a.u;
    u += 0x7FFFu + ((u >> 16) & 1u);   // RNE
    return (unsigned short)(u >> 16);
}

__device__ __forceinline__ float rcp_(float x) {
#if __has_builtin(__builtin_amdgcn_rcpf)
    return __builtin_amdgcn_rcpf(x);
#else
    return 1.0f / x;
#endif
}
// 2^x via v_exp_f32 (__exp2f is CUDA-only; HIP needs the amdgcn builtin)
__device__ __forceinline__ float exp2_(float x) {
#if __has_builtin(__builtin_amdgcn_exp2f)
    return __builtin_amdgcn_exp2f(x);
#else
    return exp2f(x);
#endif
}

// ---------- kernel 1: fused cast X->bf16 (live rows only) + weight pack ----------
// flat grid: blocks [0,8192) cast (b = bi>>8, tile = bi&255), [8192, 9728) pack.
__global__ __launch_bounds__(256) void prep(
    const float4* __restrict__ X4, uint4* __restrict__ Xb4,
    const int* __restrict__ lengths,
    const float* __restrict__ Wf, const float* __restrict__ bif, const float* __restrict__ bhf,
    const float* __restrict__ Wr, const float* __restrict__ bir, const float* __restrict__ bhr,
    unsigned short* __restrict__ Wp, float* __restrict__ bias_p)
{
    int bi = blockIdx.x;
    if (bi < 8192) {
        int b = bi >> 8, tile = bi & 255;
        int lenb = lengths[b]; lenb = lenb < 1 ? 1 : (lenb > T_ ? T_ : lenb);
        int used = (lenb + 127) & ~127;
        if (tile * 8 >= used) return;   // rows never touched by gemm (tile skipped)
        int idx = b * 65536 + tile * 256 + threadIdx.x;   // units of 8 floats
        float4 v0 = X4[2 * idx], v1 = X4[2 * idx + 1];
        union { unsigned short us[8]; uint4 u; } r;
        r.us[0] = f2bf(v0.x); r.us[1] = f2bf(v0.y); r.us[2] = f2bf(v0.z); r.us[3] = f2bf(v0.w);
        r.us[4] = f2bf(v1.x); r.us[5] = f2bf(v1.y); r.us[6] = f2bf(v1.z); r.us[7] = f2bf(v1.w);
        Xb4[idx] = r.u;
    } else {
        // Wp row n: gidx=n/48 (dir=gidx>>4, c16=gidx&15), r=n%48, ty=r/16 in {i,g,o}
        int n = bi - 8192, t = threadIdx.x;
        int gidx = n / 48, r = n % 48;
        int ty = r >> 4, cc = r & 15;
        int dir = gidx >> 4, c = (gidx & 15) * 16 + cc;
        int gate = (ty == 0) ? 0 : (ty == 1 ? 2 : 3);
        int wrow = gate * 256 + c;
        const float* W = dir ? Wr : Wf;
        Wp[n * 256 + t] = f2bf(W[wrow * 256 + t]);
        if (t == 0)
            bias_p[n] = (dir ? bir[wrow] : bif[wrow]) + (dir ? bhr[wrow] : bhf[wrow]);
    }
}

// ---------- kernel 2: fused GEMM (bf16 MFMA) + LSTM activation + masked pool ----------
// v3: barrier-free K-loop. B tile (96x256 bf16 = 48 KB) staged to LDS ONCE
// (one barrier total); A fragments loaded directly from global per kit — each
// (ks,rt) fragment instruction covers 16 rows x 64 B contiguous (fully coalesced,
// L2-hot via XCD swizzle). Explicit 1-kit-ahead A prefetch (cur/nxt registers).
// No vmcnt(0)+s_barrier drain anywhere in the K-loop (round-4/5's ~57% stall).
__global__ __launch_bounds__(256, 3) void gemm_pool(
    const unsigned short* __restrict__ Xb, const unsigned short* __restrict__ Wp,
    const float* __restrict__ bias_p, const int* __restrict__ lengths,
    float* __restrict__ psum, float* __restrict__ pmax)
{
    // B slots: (row 0..95, kc 0..31) at row*32 + (kc&24) + ((kc&7)^(row&7)), 16 B each
    __shared__ __align__(16) short Bs[96 * 256];      // 49152 B
    __shared__ float red[2][4][2][16];                // [sum/max][wave][group][col16]

    const int tid  = threadIdx.x;
    const int w    = tid >> 6;
    const int lane = tid & 63;
    const int g    = blockIdx.x;
    const int m_tile = ((g >> 7) << 3) + (g & 7);     // 0..511 (g&7 pins XCD)
    const int n_tile = (g >> 3) & 15;                 // 0..15
    const int m0   = m_tile << 7;
    const int n0   = n_tile * 96;

    const int b  = m0 >> 11;        // T = 2048
    const int t0 = m0 & 2047;
    int lenb = lengths[b]; lenb = lenb < 1 ? 1 : (lenb > T_ ? T_ : lenb);

    // fully-masked tile: mlp1 skips dead m-tiles, so write nothing at all
    if (t0 >= lenb) return;

    // ---- stage whole B tile once: 3072 chunks of 16 B = 12 rounds ----
    #pragma unroll
    for (int rr = 0; rr < 12; ++rr) {
        int s = rr * 256 + tid;
        int row = s >> 5, kcs = s & 31;
        int kc = (kcs & 24) | ((kcs & 7) ^ (row & 7));   // gather-side swizzle
        __builtin_amdgcn_global_load_lds(
            (const __attribute__((address_space(1))) void*)(Wp + (n0 + row) * 256 + kc * 8),
            (__attribute__((address_space(3))) void*)(Bs + (rr * 256 + (w << 6)) * 8),
            16, 0, 0);
    }

    f32x4 acc[2][6];
    #pragma unroll
    for (int i = 0; i < 2; ++i)
        #pragma unroll
        for (int j = 0; j < 6; ++j) acc[i][j] = (f32x4){0.f, 0.f, 0.f, 0.f};

    const int rowa = m0 + w * 32 + (lane & 15);
    const int q    = lane >> 4;
    const unsigned short* Abase = Xb + rowa * 256 + q * 8;

    bf16x8 aU[4], aV[4];   // [ks*2+rt]
    #pragma unroll
    for (int ks = 0; ks < 2; ++ks)
        #pragma unroll
        for (int rt = 0; rt < 2; ++rt)
            aU[ks * 2 + rt] = *(const bf16x8*)(Abase + rt * 16 * 256 + ks * 4 * 8);

    __syncthreads();   // the ONLY barrier: B tile (and aU) resident

    #pragma unroll
    for (int kit = 0; kit < 4; ++kit) {
        bf16x8* cur = (kit & 1) ? aV : aU;
        bf16x8* nxt = (kit & 1) ? aU : aV;
        if (kit < 3) {   // prefetch kit+1 A fragments (no barrier dependency)
            #pragma unroll
            for (int ks = 0; ks < 2; ++ks)
                #pragma unroll
                for (int rt = 0; rt < 2; ++rt)
                    nxt[ks * 2 + rt] = *(const bf16x8*)(Abase + rt * 16 * 256
                                                        + ((kit + 1) * 8 + ks * 4) * 8);
        }
        #pragma unroll
        for (int ks = 0; ks < 2; ++ks) {
            bf16x8 bfr[6];
            int kc = kit * 8 + ks * 4 + q;
            #pragma unroll
            for (int ct = 0; ct < 6; ++ct) {
                int rb = ct * 16 + (lane & 15);
                int slot = rb * 32 + (kc & 24) + ((kc & 7) ^ (rb & 7));
                bfr[ct] = *(const bf16x8*)(Bs + slot * 8);
            }
            #pragma unroll
            for (int rt = 0; rt < 2; ++rt)
                #pragma unroll
                for (int ct = 0; ct < 6; ++ct)
                    acc[rt][ct] = __builtin_amdgcn_mfma_f32_16x16x32_bf16(
                        cur[ks * 2 + rt], bfr[ct], acc[rt][ct], 0, 0, 0);
        }
    }

    // ---- epilogue: bias + LSTM pointwise (3 exp + 2 rcp per h) + masked pool ----
    const int cc = lane & 15;
    const float L2E = 1.44269504f;

    #pragma unroll
    for (int gg = 0; gg < 2; ++gg) {
        float bi = bias_p[n0 + gg * 48 + 0  + cc];
        float bg = bias_p[n0 + gg * 48 + 16 + cc];
        float bo = bias_p[n0 + gg * 48 + 32 + cc];
        float hsum = 0.f, hmax = -1e30f;
        #pragma unroll
        for (int rt = 0; rt < 2; ++rt) {
            if (t0 + w * 32 + rt * 16 >= lenb) continue;   // wave-uniform group skip
            #pragma unroll
            for (int reg = 0; reg < 4; ++reg) {
                int row = w * 32 + rt * 16 + q * 4 + reg;   // C/D: row = quad*4+reg
                int t = t0 + row;
                float iv = acc[rt][gg * 3 + 0][reg] + bi;
                float gv = acc[rt][gg * 3 + 1][reg] + bg;
                float ov = acc[rt][gg * 3 + 2][reg] + bo;
                // c = sigm(i)*tanh(g) with ONE rcp: (1-e2) / ((1+e1)(1+e2))
                float e1 = exp2_(iv * -L2E);            // e^-i
                float e2 = exp2_(gv * -2.f * L2E);      // e^-2g
                float e3 = exp2_(ov * -L2E);            // e^-o
                float cv = (1.f - e2) * rcp_((1.f + e1) * (1.f + e2));
                // h = sigm(o)*tanh(c), |c|<1: Pade(5,4) fused with sigm's denom
                float tt  = cv * cv;
                float num = cv * __builtin_fmaf(tt, tt + 105.f, 945.f);
                float den = __builtin_fmaf(tt, __builtin_fmaf(tt, 15.f, 420.f), 945.f);
                float h = num * rcp_(den * (1.f + e3));
                if (t < lenb) { hsum += h; hmax = fmaxf(hmax, h); }
            }
        }
        hsum += __shfl_xor(hsum, 16, 64);
        hmax = fmaxf(hmax, __shfl_xor(hmax, 16, 64));
        hsum += __shfl_xor(hsum, 32, 64);
        hmax = fmaxf(hmax, __shfl_xor(hmax, 32, 64));
        if (q == 0) { red[0][w][gg][cc] = hsum; red[1][w][gg][cc] = hmax; }
    }
    __syncthreads();
    if (tid < 32) {
        int gg = tid >> 4, c16 = tid & 15;
        float s  = red[0][0][gg][c16] + red[0][1][gg][c16] + red[0][2][gg][c16] + red[0][3][gg][c16];
        float mx = fmaxf(fmaxf(red[1][0][gg][c16], red[1][1][gg][c16]),
                         fmaxf(red[1][2][gg][c16], red[1][3][gg][c16]));
        int gidx = n_tile * 2 + gg;
        int col2 = (gidx >> 4) * 256 + (gidx & 15) * 16 + c16;   // dir*256 + c
        int mt = m_tile & 15;
        psum[(b * 16 + mt) * 512 + col2] = s;
        pmax[(b * 16 + mt) * 512 + col2] = mx;
    }
}

// ---------- kernel 3: finish pooling + ReLU + d1 = rel@W1^T + b1 ----------
// grid (4 neuron-tiles, 32 b); reduces only the LIVE m-tiles (dead ones unwritten).
__global__ __launch_bounds__(256) void mlp1(
    const float* __restrict__ psum, const float* __restrict__ pmax,
    const int* __restrict__ lengths,
    const float* __restrict__ W1, const float* __restrict__ b1,
    float* __restrict__ d1g)
{
    __shared__ float doc[1024];
    int nt = blockIdx.x, b = blockIdx.y, tid = threadIdx.x;
    int lenb = lengths[b]; lenb = lenb < 1 ? 1 : (lenb > T_ ? T_ : lenb);
    int cnt = (lenb + 127) >> 7;     // live m-tiles
    float invlen = 1.f / (float)lenb;
    for (int col = tid; col < 512; col += 256) {
        float s = 0.f, mx = -1e30f;
        for (int mt = 0; mt < cnt; ++mt) {
            s += psum[(b * 16 + mt) * 512 + col];
            mx = fmaxf(mx, pmax[(b * 16 + mt) * 512 + col]);
        }
        doc[col]       = fmaxf(s * invlen, 0.f);   // relu(avg_pool)
        doc[512 + col] = fmaxf(mx, 0.f);           // relu(max_pool)
    }
    __syncthreads();
    int neuron = tid >> 2, tq = tid & 3;           // 64 neurons x 4 threads
    int row = nt * 64 + neuron;
    const float4* wrow = (const float4*)(W1 + row * 1024 + tq * 256);
    const float4* dv   = (const float4*)doc + tq * 64;
    float a0 = 0.f, a1 = 0.f, a2 = 0.f, a3 = 0.f;
    #pragma unroll 4
    for (int k = 0; k < 64; ++k) {
        float4 wv = wrow[k]; float4 xv = dv[k];
        a0 += wv.x * xv.x; a1 += wv.y * xv.y; a2 += wv.z * xv.z; a3 += wv.w * xv.w;
    }
    float a = a0 + a1 + a2 + a3;
    a += __shfl_xor(a, 1, 64);
    a += __shfl_xor(a, 2, 64);
    if (tq == 0) d1g[b * 256 + row] = a + b1[row];
}

// ---------- kernel 4: out = d1@W2^T + b2 ----------
__global__ __launch_bounds__(256) void mlp2(
    const float* __restrict__ d1g,
    const float* __restrict__ W2, const float* __restrict__ b2,
    float* __restrict__ out)
{
    __shared__ float d1s[256];
    int b = blockIdx.x, tid = threadIdx.x;
    d1s[tid] = d1g[b * 256 + tid];
    __syncthreads();
    int j = tid >> 3, tq = tid & 7;   // 32 j-slots (20 active) x 8 threads
    float a = 0.f;
    if (j < LBL_) {
        const float4* wr = (const float4*)(W2 + j * 256) + tq * 8;
        const float4* dd = (const float4*)d1s + tq * 8;
        #pragma unroll
        for (int k = 0; k < 8; ++k) {
            float4 wv = wr[k]; float4 xv = dd[k];
            a += wv.x * xv.x + wv.y * xv.y + wv.z * xv.z + wv.w * xv.w;
        }
    }
    a += __shfl_xor(a, 1, 64);
    a += __shfl_xor(a, 2, 64);
    a += __shfl_xor(a, 4, 64);
    if (j < LBL_ && tq == 0) out[b * LBL_ + j] = a + b2[j];
}

// ---------- workspace layout (bytes) ----------
#define XB_OFF   0u
#define WP_OFF   33554432u          // 65536*256*2
#define BIAS_OFF 34340864u          // + 1536*256*2
#define PSUM_OFF 34347008u          // + 1536*4
#define PMAX_OFF 35395584u          // + 32*16*512*4
#define D1_OFF   36444160u          // + 32*16*512*4

extern "C" void kernel_launch(void* const* d_in, const int* in_sizes, int n_in,
                              void* d_out, int out_size, void* d_ws, size_t ws_size,
                              hipStream_t stream) {
    (void)in_sizes; (void)n_in; (void)out_size; (void)ws_size;
    const float* X      = (const float*)d_in[0];
    const int*   lens   = (const int*)d_in[1];
    const float* W_ih_f = (const float*)d_in[2];
    const float* b_ih_f = (const float*)d_in[3];
    const float* b_hh_f = (const float*)d_in[4];
    const float* W_ih_r = (const float*)d_in[5];
    const float* b_ih_r = (const float*)d_in[6];
    const float* b_hh_r = (const float*)d_in[7];
    const float* W1     = (const float*)d_in[8];
    const float* b1     = (const float*)d_in[9];
    const float* W2     = (const float*)d_in[10];
    const float* b2     = (const float*)d_in[11];
    float* out = (float*)d_out;

    char* ws = (char*)d_ws;
    unsigned short* Xb     = (unsigned short*)(ws + XB_OFF);
    unsigned short* Wp     = (unsigned short*)(ws + WP_OFF);
    float*          bias_p = (float*)(ws + BIAS_OFF);
    float*          psum   = (float*)(ws + PSUM_OFF);
    float*          pmax   = (float*)(ws + PMAX_OFF);
    float*          d1g    = (float*)(ws + D1_OFF);

    prep<<<dim3(8192 + NPACK_), 256, 0, stream>>>(
        (const float4*)X, (uint4*)Xb, lens,
        W_ih_f, b_ih_f, b_hh_f, W_ih_r, b_ih_r, b_hh_r, Wp, bias_p);
    gemm_pool<<<dim3(8192), 256, 0, stream>>>(Xb, Wp, bias_p, lens, psum, pmax);
    mlp1<<<dim3(4, 32), 256, 0, stream>>>(psum, pmax, lens, W1, b1, d1g);
    mlp2<<<dim3(B_), 256, 0, stream>>>(d1g, W2, b2, out);
}

// Round 7
// 176.110 us; speedup vs baseline: 1.1594x; 1.1594x over previous
//
#include <hip/hip_runtime.h>
#include <stdint.h>

// Problem constants
#define B_   32
#define T_   2048
#define E_   256
#define H_   256
#define LBL_ 20
#define M_   (B_ * T_)      // 65536 rows
#define NPACK_ 1536         // 2 dirs * 3 gates (i,g,o) * 256

typedef __attribute__((ext_vector_type(8))) short bf16x8;
typedef __attribute__((ext_vector_type(4))) float f32x4;

__device__ __forceinline__ unsigned short f2bf(float f) {
    union { float f; unsigned int u; } a; a.f = f;
    unsigned int u = a.u;
    u += 0x7FFFu + ((u >> 16) & 1u);   // RNE
    return (unsigned short)(u >> 16);
}

__device__ __forceinline__ float rcp_(float x) {
#if __has_builtin(__builtin_amdgcn_rcpf)
    return __builtin_amdgcn_rcpf(x);
#else
    return 1.0f / x;
#endif
}
__device__ __forceinline__ float exp2_(float x) {
#if __has_builtin(__builtin_amdgcn_exp2f)
    return __builtin_amdgcn_exp2f(x);
#else
    return exp2f(x);
#endif
}

// ---------- kernel 1: cast X->bf16 (live rows) + weight pack + live-tile list ----------
// flat grid: [0,8192) cast; [8192, 9728) pack; block 9728 builds the live list.
__global__ __launch_bounds__(256) void prep(
    const float4* __restrict__ X4, uint4* __restrict__ Xb4,
    const int* __restrict__ lengths,
    const float* __restrict__ Wf, const float* __restrict__ bif, const float* __restrict__ bhf,
    const float* __restrict__ Wr, const float* __restrict__ bir, const float* __restrict__ bhr,
    unsigned short* __restrict__ Wp, float* __restrict__ bias_p,
    int* __restrict__ live)   // live[0] = nlive; live[1..] = (lenb<<9)|(b*16+mt)
{
    int bi = blockIdx.x;
    if (bi < 8192) {
        int b = bi >> 8, tile = bi & 255;
        int lenb = lengths[b]; lenb = lenb < 1 ? 1 : (lenb > T_ ? T_ : lenb);
        int used = (lenb + 127) & ~127;
        if (tile * 8 >= used) return;   // rows never touched by gemm
        int idx = b * 65536 + tile * 256 + threadIdx.x;   // units of 8 floats
        float4 v0 = X4[2 * idx], v1 = X4[2 * idx + 1];
        union { unsigned short us[8]; uint4 u; } r;
        r.us[0] = f2bf(v0.x); r.us[1] = f2bf(v0.y); r.us[2] = f2bf(v0.z); r.us[3] = f2bf(v0.w);
        r.us[4] = f2bf(v1.x); r.us[5] = f2bf(v1.y); r.us[6] = f2bf(v1.z); r.us[7] = f2bf(v1.w);
        Xb4[idx] = r.u;
    } else if (bi < 8192 + NPACK_) {
        int n = bi - 8192, t = threadIdx.x;
        int gidx = n / 48, r = n % 48;
        int ty = r >> 4, cc = r & 15;
        int dir = gidx >> 4, c = (gidx & 15) * 16 + cc;
        int gate = (ty == 0) ? 0 : (ty == 1 ? 2 : 3);
        int wrow = gate * 256 + c;
        const float* W = dir ? Wr : Wf;
        Wp[n * 256 + t] = f2bf(W[wrow * 256 + t]);
        if (t == 0)
            bias_p[n] = (dir ? bir[wrow] : bif[wrow]) + (dir ? bhr[wrow] : bhf[wrow]);
    } else {
        // build compact list of live (b, m_tile) items with packed length
        __shared__ int cnts[32], offs[32], lens[32];
        int t = threadIdx.x;
        if (t < 32) {
            int lenb = lengths[t]; lenb = lenb < 1 ? 1 : (lenb > T_ ? T_ : lenb);
            lens[t] = lenb;
            cnts[t] = (lenb + 127) >> 7;
        }
        __syncthreads();
        if (t == 0) {
            int acc = 0;
            for (int b = 0; b < 32; ++b) { offs[b] = acc; acc += cnts[b]; }
            live[0] = acc;
        }
        __syncthreads();
        if (t < 32) {
            int o = offs[t], lenb = lens[t];
            for (int k = 0; k < cnts[t]; ++k)
                live[1 + o + k] = (lenb << 9) | (t * 16 + k);
        }
    }
}

// ---------- kernel 2: persistent-B fused GEMM + LSTM activation + masked pool ----------
// grid = 768 = 16 n_tiles x 48 workers = exactly 3 blocks/CU (LDS 50 KB).
// Each block stages its 96x256 B tile to LDS ONCE, then loops over live (b,mt)
// items (static stride-48 slice of the prep-built list). A fragments from global
// (L2/L3-hot) with a cur/nxt register pipeline that crosses tile boundaries:
// kit3 prefetches the NEXT tile's kit0; the epilogue covers that latency.
// One barrier per tile (red reduction, parity-buffered); K-loop barrier-free.
__global__ __launch_bounds__(256, 3) void gemm_pool(
    const unsigned short* __restrict__ Xb, const unsigned short* __restrict__ Wp,
    const float* __restrict__ bias_p, const int* __restrict__ live,
    float* __restrict__ psum, float* __restrict__ pmax)
{
    // B slots: (row 0..95, kc 0..31) at row*32 + (kc&24) + ((kc&7)^(row&7)), 16 B each
    __shared__ __align__(16) short Bs[96 * 256];          // 49152 B
    __shared__ float red[2][4][2][16][2];                 // [parity][wave][gg][cc][sum|max]

    const int tid    = threadIdx.x;
    const int w      = tid >> 6;
    const int lane   = tid & 63;
    const int n_tile = blockIdx.x & 15;
    const int worker = blockIdx.x >> 4;    // 0..47
    const int n0     = n_tile * 96;
    const int q      = lane >> 4;
    const int cc     = lane & 15;

    // ---- stage whole B tile once: 3072 chunks of 16 B = 12 rounds ----
    #pragma unroll
    for (int rr = 0; rr < 12; ++rr) {
        int s = rr * 256 + tid;
        int row = s >> 5, kcs = s & 31;
        int kc = (kcs & 24) | ((kcs & 7) ^ (row & 7));   // gather-side swizzle
        __builtin_amdgcn_global_load_lds(
            (const __attribute__((address_space(1))) void*)(Wp + (n0 + row) * 256 + kc * 8),
            (__attribute__((address_space(3))) void*)(Bs + (rr * 256 + (w << 6)) * 8),
            16, 0, 0);
    }

    // hoist per-column biases (fixed per block)
    float bI[2], bG[2], bO[2];
    #pragma unroll
    for (int gg = 0; gg < 2; ++gg) {
        bI[gg] = bias_p[n0 + gg * 48 + 0  + cc];
        bG[gg] = bias_p[n0 + gg * 48 + 16 + cc];
        bO[gg] = bias_p[n0 + gg * 48 + 32 + cc];
    }

    const int nlive = live[0];
    const int* list = live + 1;

    int j = worker;
    int item = (j < nlive) ? list[j] : -1;
    const unsigned short* Ab = Xb;
    bf16x8 aU[4], aV[4];   // [ks*2+rt]
    if (item >= 0) {
        Ab = Xb + (((item & 511) << 7) + w * 32 + (lane & 15)) * 256 + q * 8;
        #pragma unroll
        for (int ks = 0; ks < 2; ++ks)
            #pragma unroll
            for (int rt = 0; rt < 2; ++rt)
                aU[ks * 2 + rt] = *(const bf16x8*)(Ab + rt * 16 * 256 + ks * 4 * 8);
    }

    __syncthreads();   // B tile resident (compiler drains vmcnt before s_barrier)

    int par = 0;
    const float L2E = 1.44269504f;

    while (item >= 0) {
        int jn = j + 48;
        int itemn = (jn < nlive) ? list[jn] : -1;
        const unsigned short* Abn = (itemn >= 0)
            ? Xb + (((itemn & 511) << 7) + w * 32 + (lane & 15)) * 256 + q * 8
            : Ab;

        f32x4 acc[2][6];
        #pragma unroll
        for (int i = 0; i < 2; ++i)
            #pragma unroll
            for (int jj = 0; jj < 6; ++jj) acc[i][jj] = (f32x4){0.f, 0.f, 0.f, 0.f};

        #pragma unroll
        for (int kit = 0; kit < 4; ++kit) {
            bf16x8* cur = (kit & 1) ? aV : aU;
            bf16x8* nxt = (kit & 1) ? aU : aV;
            if (kit < 3) {          // prefetch kit+1 of this tile
                #pragma unroll
                for (int ks = 0; ks < 2; ++ks)
                    #pragma unroll
                    for (int rt = 0; rt < 2; ++rt)
                        nxt[ks * 2 + rt] = *(const bf16x8*)(Ab + rt * 16 * 256
                                                            + ((kit + 1) * 8 + ks * 4) * 8);
            } else {                // kit3: prefetch NEXT tile's kit0 (lands in aU)
                #pragma unroll
                for (int ks = 0; ks < 2; ++ks)
                    #pragma unroll
                    for (int rt = 0; rt < 2; ++rt)
                        nxt[ks * 2 + rt] = *(const bf16x8*)(Abn + rt * 16 * 256 + ks * 4 * 8);
            }
            #pragma unroll
            for (int ks = 0; ks < 2; ++ks) {
                bf16x8 bfr[6];
                int kc = kit * 8 + ks * 4 + q;
                #pragma unroll
                for (int ct = 0; ct < 6; ++ct) {
                    int rb = ct * 16 + (lane & 15);
                    int slot = rb * 32 + (kc & 24) + ((kc & 7) ^ (rb & 7));
                    bfr[ct] = *(const bf16x8*)(Bs + slot * 8);
                }
                #pragma unroll
                for (int rt = 0; rt < 2; ++rt)
                    #pragma unroll
                    for (int ct = 0; ct < 6; ++ct)
                        acc[rt][ct] = __builtin_amdgcn_mfma_f32_16x16x32_bf16(
                            cur[ks * 2 + rt], bfr[ct], acc[rt][ct], 0, 0, 0);
            }
        }

        // ---- epilogue: bias + LSTM pointwise + masked sum/max pool ----
        const int idx9 = item & 511;
        const int lenb = item >> 9;
        const int t0   = (idx9 & 15) << 7;

        #pragma unroll
        for (int gg = 0; gg < 2; ++gg) {
            float hsum = 0.f, hmax = -1e30f;
            #pragma unroll
            for (int rt = 0; rt < 2; ++rt) {
                if (t0 + w * 32 + rt * 16 >= lenb) continue;   // wave-uniform group skip
                #pragma unroll
                for (int reg = 0; reg < 4; ++reg) {
                    int row = w * 32 + rt * 16 + q * 4 + reg;   // C/D: row = quad*4+reg
                    int t = t0 + row;
                    float iv = acc[rt][gg * 3 + 0][reg] + bI[gg];
                    float gv = acc[rt][gg * 3 + 1][reg] + bG[gg];
                    float ov = acc[rt][gg * 3 + 2][reg] + bO[gg];
                    float e1 = exp2_(iv * -L2E);            // e^-i
                    float e2 = exp2_(gv * -2.f * L2E);      // e^-2g
                    float e3 = exp2_(ov * -L2E);            // e^-o
                    float cv = (1.f - e2) * rcp_((1.f + e1) * (1.f + e2));
                    float tt  = cv * cv;                     // |cv|<1: Pade(5,4)
                    float num = cv * __builtin_fmaf(tt, tt + 105.f, 945.f);
                    float den = __builtin_fmaf(tt, __builtin_fmaf(tt, 15.f, 420.f), 945.f);
                    float h = num * rcp_(den * (1.f + e3));
                    if (t < lenb) { hsum += h; hmax = fmaxf(hmax, h); }
                }
            }
            hsum += __shfl_xor(hsum, 16, 64);
            hmax = fmaxf(hmax, __shfl_xor(hmax, 16, 64));
            hsum += __shfl_xor(hsum, 32, 64);
            hmax = fmaxf(hmax, __shfl_xor(hmax, 32, 64));
            if (q == 0) { red[par][w][gg][cc][0] = hsum; red[par][w][gg][cc][1] = hmax; }
        }
        __syncthreads();   // the only per-tile barrier
        if (tid < 32) {
            int gg = tid >> 4, c16 = tid & 15;
            float s  = red[par][0][gg][c16][0] + red[par][1][gg][c16][0]
                     + red[par][2][gg][c16][0] + red[par][3][gg][c16][0];
            float mx = fmaxf(fmaxf(red[par][0][gg][c16][1], red[par][1][gg][c16][1]),
                             fmaxf(red[par][2][gg][c16][1], red[par][3][gg][c16][1]));
            int gidx = n_tile * 2 + gg;
            int col2 = (gidx >> 4) * 256 + (gidx & 15) * 16 + c16;   // dir*256 + c
            psum[idx9 * 512 + col2] = s;
            pmax[idx9 * 512 + col2] = mx;
        }
        par ^= 1;          // parity-buffered red: no second barrier needed
        j = jn; item = itemn; Ab = Abn;
    }
}

// ---------- kernel 3: finish pooling + ReLU + d1 = rel@W1^T + b1 ----------
__global__ __launch_bounds__(256) void mlp1(
    const float* __restrict__ psum, const float* __restrict__ pmax,
    const int* __restrict__ lengths,
    const float* __restrict__ W1, const float* __restrict__ b1,
    float* __restrict__ d1g)
{
    __shared__ float doc[1024];
    int nt = blockIdx.x, b = blockIdx.y, tid = threadIdx.x;
    int lenb = lengths[b]; lenb = lenb < 1 ? 1 : (lenb > T_ ? T_ : lenb);
    int cnt = (lenb + 127) >> 7;     // live m-tiles
    float invlen = 1.f / (float)lenb;
    for (int col = tid; col < 512; col += 256) {
        float s = 0.f, mx = -1e30f;
        for (int mt = 0; mt < cnt; ++mt) {
            s += psum[(b * 16 + mt) * 512 + col];
            mx = fmaxf(mx, pmax[(b * 16 + mt) * 512 + col]);
        }
        doc[col]       = fmaxf(s * invlen, 0.f);   // relu(avg_pool)
        doc[512 + col] = fmaxf(mx, 0.f);           // relu(max_pool)
    }
    __syncthreads();
    int neuron = tid >> 2, tq = tid & 3;           // 64 neurons x 4 threads
    int row = nt * 64 + neuron;
    const float4* wrow = (const float4*)(W1 + row * 1024 + tq * 256);
    const float4* dv   = (const float4*)doc + tq * 64;
    float a0 = 0.f, a1 = 0.f, a2 = 0.f, a3 = 0.f;
    #pragma unroll 4
    for (int k = 0; k < 64; ++k) {
        float4 wv = wrow[k]; float4 xv = dv[k];
        a0 += wv.x * xv.x; a1 += wv.y * xv.y; a2 += wv.z * xv.z; a3 += wv.w * xv.w;
    }
    float a = a0 + a1 + a2 + a3;
    a += __shfl_xor(a, 1, 64);
    a += __shfl_xor(a, 2, 64);
    if (tq == 0) d1g[b * 256 + row] = a + b1[row];
}

// ---------- kernel 4: out = d1@W2^T + b2 ----------
__global__ __launch_bounds__(256) void mlp2(
    const float* __restrict__ d1g,
    const float* __restrict__ W2, const float* __restrict__ b2,
    float* __restrict__ out)
{
    __shared__ float d1s[256];
    int b = blockIdx.x, tid = threadIdx.x;
    d1s[tid] = d1g[b * 256 + tid];
    __syncthreads();
    int j = tid >> 3, tq = tid & 7;   // 32 j-slots (20 active) x 8 threads
    float a = 0.f;
    if (j < LBL_) {
        const float4* wr = (const float4*)(W2 + j * 256) + tq * 8;
        const float4* dd = (const float4*)d1s + tq * 8;
        #pragma unroll
        for (int k = 0; k < 8; ++k) {
            float4 wv = wr[k]; float4 xv = dd[k];
            a += wv.x * xv.x + wv.y * xv.y + wv.z * xv.z + wv.w * xv.w;
        }
    }
    a += __shfl_xor(a, 1, 64);
    a += __shfl_xor(a, 2, 64);
    a += __shfl_xor(a, 4, 64);
    if (j < LBL_ && tq == 0) out[b * LBL_ + j] = a + b2[j];
}

// ---------- workspace layout (bytes) ----------
#define XB_OFF   0u
#define WP_OFF   33554432u          // 65536*256*2
#define BIAS_OFF 34340864u          // + 1536*256*2
#define PSUM_OFF 34347008u          // + 1536*4
#define PMAX_OFF 35395584u          // + 32*16*512*4
#define D1_OFF   36444160u          // + 32*16*512*4
#define LIVE_OFF 36476928u          // + 32*256*4

extern "C" void kernel_launch(void* const* d_in, const int* in_sizes, int n_in,
                              void* d_out, int out_size, void* d_ws, size_t ws_size,
                              hipStream_t stream) {
    (void)in_sizes; (void)n_in; (void)out_size; (void)ws_size;
    const float* X      = (const float*)d_in[0];
    const int*   lens   = (const int*)d_in[1];
    const float* W_ih_f = (const float*)d_in[2];
    const float* b_ih_f = (const float*)d_in[3];
    const float* b_hh_f = (const float*)d_in[4];
    const float* W_ih_r = (const float*)d_in[5];
    const float* b_ih_r = (const float*)d_in[6];
    const float* b_hh_r = (const float*)d_in[7];
    const float* W1     = (const float*)d_in[8];
    const float* b1     = (const float*)d_in[9];
    const float* W2     = (const float*)d_in[10];
    const float* b2     = (const float*)d_in[11];
    float* out = (float*)d_out;

    char* ws = (char*)d_ws;
    unsigned short* Xb     = (unsigned short*)(ws + XB_OFF);
    unsigned short* Wp     = (unsigned short*)(ws + WP_OFF);
    float*          bias_p = (float*)(ws + BIAS_OFF);
    float*          psum   = (float*)(ws + PSUM_OFF);
    float*          pmax   = (float*)(ws + PMAX_OFF);
    float*          d1g    = (float*)(ws + D1_OFF);
    int*            live   = (int*)(ws + LIVE_OFF);

    prep<<<dim3(8192 + NPACK_ + 1), 256, 0, stream>>>(
        (const float4*)X, (uint4*)Xb, lens,
        W_ih_f, b_ih_f, b_hh_f, W_ih_r, b_ih_r, b_hh_r, Wp, bias_p, live);
    gemm_pool<<<dim3(768), 256, 0, stream>>>(Xb, Wp, bias_p, live, psum, pmax);
    mlp1<<<dim3(4, 32), 256, 0, stream>>>(psum, pmax, lens, W1, b1, d1g);
    mlp2<<<dim3(B_), 256, 0, stream>>>(d1g, W2, b2, out);
}